// Round 2
// baseline (322.501 us; speedup 1.0000x reference)
//
#include <hip/hip_runtime.h>

typedef unsigned short u16;
typedef __attribute__((ext_vector_type(8))) short bf16x8;
typedef __attribute__((ext_vector_type(4))) float f32x4;
typedef __attribute__((ext_vector_type(8))) unsigned short ushort8;

#define SQ 4096
#define HQ 128

__device__ __forceinline__ u16 f2b(float f) {
  unsigned int u = __float_as_uint(f);
  unsigned int r = (u + 0x7fffu + ((u >> 16) & 1u)) >> 16;  // RNE bf16
  return (u16)r;
}

// x f32 -> bf16, 8 elems/thread
__global__ __launch_bounds__(256) void k_convx(const float* __restrict__ x, u16* __restrict__ xb) {
  long i = (long)(blockIdx.x * 256 + threadIdx.x) * 8;
  float4 a = *(const float4*)(x + i);
  float4 c = *(const float4*)(x + i + 4);
  ushort8 o;
  o[0]=f2b(a.x); o[1]=f2b(a.y); o[2]=f2b(a.z); o[3]=f2b(a.w);
  o[4]=f2b(c.x); o[5]=f2b(c.y); o[6]=f2b(c.z); o[7]=f2b(c.w);
  *(ushort8*)(xb + i) = o;
}

// Wt[z][n][k] = W_z[k][n]  (bf16, B^T layout for MFMA B-frags)
__global__ __launch_bounds__(256) void k_wt(const float* __restrict__ Wq, const float* __restrict__ Wk,
                                            const float* __restrict__ Wv, u16* __restrict__ wt) {
  int idx = blockIdx.x * 256 + threadIdx.x;
  int z = idx >> 17, r = idx & 131071, n = r >> 10, k = r & 1023;
  const float* W = (z == 0) ? Wq : (z == 1) ? Wk : Wv;
  wt[idx] = f2b(W[k * 128 + n]);
}

// C = xb @ Wz^T(stored as Wt[n][k]); 128x128 tile, 4 waves 2x2, 16x16x32 bf16
__global__ __launch_bounds__(256) void k_proj(const u16* __restrict__ xb, const u16* __restrict__ wt,
                                              u16* __restrict__ qb, u16* __restrict__ kb,
                                              u16* __restrict__ vt) {
  int mt = blockIdx.x, z = blockIdx.y;
  int w = threadIdx.x >> 6, lane = threadIdx.x & 63;
  int wr = w >> 1, wc = w & 1;
  int m0 = mt * 128 + wr * 64;
  int n0 = wc * 64;
  int lr = lane & 15, lg = lane >> 4;
  const u16* Wz = wt + z * 131072;
  f32x4 acc[4][4];
  for (int i = 0; i < 4; ++i) for (int j = 0; j < 4; ++j) acc[i][j] = (f32x4){0.f, 0.f, 0.f, 0.f};
  for (int k0 = 0; k0 < 1024; k0 += 32) {
    bf16x8 a[4], bfr[4];
    for (int i = 0; i < 4; ++i)
      a[i] = *(const bf16x8*)(xb + (long)(m0 + i * 16 + lr) * 1024 + k0 + lg * 8);
    for (int j = 0; j < 4; ++j)
      bfr[j] = *(const bf16x8*)(Wz + (long)(n0 + j * 16 + lr) * 1024 + k0 + lg * 8);
    for (int i = 0; i < 4; ++i)
      for (int j = 0; j < 4; ++j)
        acc[i][j] = __builtin_amdgcn_mfma_f32_16x16x32_bf16(a[i], bfr[j], acc[i][j], 0, 0, 0);
  }
  for (int i = 0; i < 4; ++i)
    for (int j = 0; j < 4; ++j)
      for (int r = 0; r < 4; ++r) {
        int m = m0 + i * 16 + lg * 4 + r;   // C layout: row=(lane>>4)*4+reg, col=lane&15
        int n = n0 + j * 16 + lr;
        u16 v = f2b(acc[i][j][r]);
        if (z == 0) qb[(long)m * 128 + n] = v;
        else if (z == 1) kb[(long)m * 128 + n] = v;
        else { int bb = m >> 12, sR = m & 4095; vt[(long)bb * 524288 + (long)n * 4096 + sR] = v; }
      }
}

// flash attention, split-K: block = one (b, 16-row q-group); 4 waves round-robin
// over 64-key tiles; LDS log-sum-exp merge at the end.
__global__ __launch_bounds__(256, 4) void k_attn(const u16* __restrict__ qb, const u16* __restrict__ kb,
                                                 const u16* __restrict__ vt, const int* __restrict__ kmask,
                                                 float* __restrict__ out) {
  const float SCALE_LOG2 = 0.08838834764831845f * 1.4426950408889634f;
  const float THR = 8.0f;  // defer-max threshold (log2 domain)
  int qt = gridDim.x - 1 - blockIdx.x;  // heavy q-groups dispatched first
  int b = blockIdx.y;
  int w = threadIdx.x >> 6, lane = threadIdx.x & 63;
  int lr = lane & 15, lg = lane >> 4;
  int qrow0 = qt * 16;
  const u16* Q = qb + ((long)(b * SQ + qrow0)) * HQ;
  const u16* K = kb + (long)b * SQ * HQ;
  const u16* V = vt + (long)b * HQ * SQ;   // V^T: [128][SQ]
  const int* msk = kmask + b * SQ;

  bf16x8 aq[4];
#pragma unroll
  for (int c = 0; c < 4; ++c) aq[c] = *(const bf16x8*)(Q + lr * HQ + c * 32 + lg * 8);

  f32x4 o[8];
#pragma unroll
  for (int n = 0; n < 8; ++n) o[n] = (f32x4){0.f, 0.f, 0.f, 0.f};
  float m_run[4], l_run[4];
#pragma unroll
  for (int r = 0; r < 4; ++r) { m_run[r] = -3e38f; l_run[r] = 0.f; }

  __shared__ __align__(16) u16 plds[4][16][80];   // per-wave P tile (16 q x 64 k), padded
  __shared__ float sm[4][16], sl[4][16];
  __shared__ float so[4][16][68];                 // partial-O merge buffer (half head dim)

  int nkeys = qrow0 + 16;
  int nkt = (nkeys + 63) >> 6;
  for (int kt = w; kt < nkt; kt += 4) {
    int kb0 = kt * 64;
    // ---- QK^T: 16 MFMAs -> s[h][r] (h = 16-key half, r = q-row reg)
    f32x4 s[4];
#pragma unroll
    for (int h = 0; h < 4; ++h) {
      f32x4 acc = (f32x4){0.f, 0.f, 0.f, 0.f};
      const u16* Kp = K + (long)(kb0 + h * 16 + lr) * HQ + lg * 8;
#pragma unroll
      for (int c = 0; c < 4; ++c) {
        bf16x8 bk = *(const bf16x8*)(Kp + c * 32);
        acc = __builtin_amdgcn_mfma_f32_16x16x32_bf16(aq[c], bk, acc, 0, 0, 0);
      }
      s[h] = acc;
    }
    int mv[4];
#pragma unroll
    for (int h = 0; h < 4; ++h) mv[h] = msk[kb0 + h * 16 + lr];
    // ---- mask + scale + row-max (4 shuffles per row over 64 keys)
    float sv[4][4], tr[4];
#pragma unroll
    for (int r = 0; r < 4; ++r) {
      int qr = qrow0 + lg * 4 + r;
      float tt = -3e38f;
#pragma unroll
      for (int h = 0; h < 4; ++h) {
        float sx = ((kb0 + h * 16 + lr) <= qr && mv[h] != 0) ? s[h][r] * SCALE_LOG2 : -3e38f;
        sv[h][r] = sx;
        tt = fmaxf(tt, sx);
      }
      tt = fmaxf(tt, __shfl_xor(tt, 1));
      tt = fmaxf(tt, __shfl_xor(tt, 2));
      tt = fmaxf(tt, __shfl_xor(tt, 4));
      tt = fmaxf(tt, __shfl_xor(tt, 8));
      tr[r] = tt;
    }
    // ---- defer-max: only rescale when some row grew past THR
    bool grow = (tr[0] > m_run[0] + THR) || (tr[1] > m_run[1] + THR) ||
                (tr[2] > m_run[2] + THR) || (tr[3] > m_run[3] + THR);
    if (__any(grow)) {
      float alpha[4];
#pragma unroll
      for (int r = 0; r < 4; ++r) {
        float mnew = fmaxf(m_run[r], tr[r]);
        alpha[r] = __builtin_exp2f(m_run[r] - mnew);
        m_run[r] = mnew;
        l_run[r] *= alpha[r];
      }
#pragma unroll
      for (int n = 0; n < 8; ++n)
#pragma unroll
        for (int r = 0; r < 4; ++r) o[n][r] *= alpha[r];
    }
    // ---- P = exp2(s - m); row-sum; write P tile to LDS (A-frag relayout)
#pragma unroll
    for (int r = 0; r < 4; ++r) {
      float rs = 0.f;
#pragma unroll
      for (int h = 0; h < 4; ++h) {
        float p = (sv[h][r] < -1e37f) ? 0.f : __builtin_exp2f(sv[h][r] - m_run[r]);
        plds[w][lg * 4 + r][h * 16 + lr] = f2b(p);
        rs += p;
      }
      rs += __shfl_xor(rs, 1);
      rs += __shfl_xor(rs, 2);
      rs += __shfl_xor(rs, 4);
      rs += __shfl_xor(rs, 8);
      l_run[r] += rs;
    }
    // ---- PV: 16 MFMAs (two K=32 chains over the 64 keys)
    bf16x8 ap0 = *(const bf16x8*)(&plds[w][lr][lg * 8]);
    bf16x8 ap1 = *(const bf16x8*)(&plds[w][lr][32 + lg * 8]);
#pragma unroll
    for (int n = 0; n < 8; ++n) {
      const u16* Vp = V + (long)(n * 16 + lr) * SQ + kb0 + lg * 8;
      bf16x8 bv0 = *(const bf16x8*)(Vp);
      bf16x8 bv1 = *(const bf16x8*)(Vp + 32);
      o[n] = __builtin_amdgcn_mfma_f32_16x16x32_bf16(ap0, bv0, o[n], 0, 0, 0);
      o[n] = __builtin_amdgcn_mfma_f32_16x16x32_bf16(ap1, bv1, o[n], 0, 0, 0);
    }
  }

  // ---- split-K merge across the 4 waves (log-sum-exp), two half-head passes
  if (lr == 0) {
#pragma unroll
    for (int r = 0; r < 4; ++r) { sm[w][lg * 4 + r] = m_run[r]; sl[w][lg * 4 + r] = l_run[r]; }
  }
#pragma unroll
  for (int n = 0; n < 4; ++n)
#pragma unroll
    for (int r = 0; r < 4; ++r) so[w][lg * 4 + r][n * 16 + lr] = o[n][r];
  __syncthreads();
  int y = w * 4 + lg;
  float m0s = sm[0][y], m1s = sm[1][y], m2s = sm[2][y], m3s = sm[3][y];
  float mstar = fmaxf(fmaxf(m0s, m1s), fmaxf(m2s, m3s));
  float e0 = __builtin_exp2f(m0s - mstar), e1 = __builtin_exp2f(m1s - mstar);
  float e2 = __builtin_exp2f(m2s - mstar), e3 = __builtin_exp2f(m3s - mstar);
  float L = sl[0][y] * e0 + sl[1][y] * e1 + sl[2][y] * e2 + sl[3][y] * e3;
  float inv = 1.0f / L;
  float* orow = out + ((long)(b * SQ + qrow0 + y)) * HQ;
#pragma unroll
  for (int j = 0; j < 4; ++j) {
    int c = j * 16 + lr;
    float acc = so[0][y][c] * e0 + so[1][y][c] * e1 + so[2][y][c] * e2 + so[3][y][c] * e3;
    orow[c] = acc * inv;
  }
  __syncthreads();
#pragma unroll
  for (int n = 0; n < 4; ++n)
#pragma unroll
    for (int r = 0; r < 4; ++r) so[w][lg * 4 + r][n * 16 + lr] = o[n + 4][r];
  __syncthreads();
#pragma unroll
  for (int j = 0; j < 4; ++j) {
    int c = j * 16 + lr;
    float acc = so[0][y][c] * e0 + so[1][y][c] * e1 + so[2][y][c] * e2 + so[3][y][c] * e3;
    orow[64 + c] = acc * inv;
  }
}

extern "C" void kernel_launch(void* const* d_in, const int* in_sizes, int n_in,
                              void* d_out, int out_size, void* d_ws, size_t ws_size,
                              hipStream_t stream) {
  const float* x  = (const float*)d_in[0];
  const float* Wq = (const float*)d_in[1];
  const float* Wk = (const float*)d_in[2];
  const float* Wv = (const float*)d_in[3];
  const int* kmask = (const int*)d_in[4];
  char* ws = (char*)d_ws;
  u16* xb = (u16*)ws;                         // 32 MB: x as bf16
  u16* wt = (u16*)(ws + 33554432);            // 768 KB: Wt[3][128][1024]
  u16* qb = (u16*)(ws + 34340864);            // 4 MB: Q bf16 [16384][128]
  u16* kb = (u16*)(ws + 38535168);            // 4 MB: K bf16 [16384][128]
  u16* vt = (u16*)(ws + 42729472);            // 4 MB: V^T bf16 [4][128][4096]
  float* out = (float*)d_out;

  k_convx<<<8192, 256, 0, stream>>>(x, xb);
  k_wt<<<1536, 256, 0, stream>>>(Wq, Wk, Wv, wt);
  k_proj<<<dim3(128, 3), 256, 0, stream>>>(xb, wt, qb, kb, vt);
  k_attn<<<dim3(256, 4), 256, 0, stream>>>(qb, kb, vt, kmask, out);
}

// Round 3
// 264.164 us; speedup vs baseline: 1.2208x; 1.2208x over previous
//
#include <hip/hip_runtime.h>

typedef unsigned short u16;
typedef __attribute__((ext_vector_type(8))) short bf16x8;
typedef __attribute__((ext_vector_type(4))) float f32x4;
typedef __attribute__((ext_vector_type(8))) unsigned short ushort8;

#define SQ 4096
#define HQ 128

__device__ __forceinline__ u16 f2b(float f) {
  unsigned int u = __float_as_uint(f);
  unsigned int r = (u + 0x7fffu + ((u >> 16) & 1u)) >> 16;  // RNE bf16
  return (u16)r;
}

__device__ __forceinline__ void gload_lds16(const u16* gsrc, u16* ldst) {
  __builtin_amdgcn_global_load_lds((const __attribute__((address_space(1))) void*)gsrc,
                                   (__attribute__((address_space(3))) void*)ldst, 16, 0, 0);
}

// x f32 -> bf16, 8 elems/thread
__global__ __launch_bounds__(256) void k_convx(const float* __restrict__ x, u16* __restrict__ xb) {
  long i = (long)(blockIdx.x * 256 + threadIdx.x) * 8;
  float4 a = *(const float4*)(x + i);
  float4 c = *(const float4*)(x + i + 4);
  ushort8 o;
  o[0]=f2b(a.x); o[1]=f2b(a.y); o[2]=f2b(a.z); o[3]=f2b(a.w);
  o[4]=f2b(c.x); o[5]=f2b(c.y); o[6]=f2b(c.z); o[7]=f2b(c.w);
  *(ushort8*)(xb + i) = o;
}

// Wt[z][n][k] = W_z[k][n]  (bf16, B^T layout for MFMA B-frags)
__global__ __launch_bounds__(256) void k_wt(const float* __restrict__ Wq, const float* __restrict__ Wk,
                                            const float* __restrict__ Wv, u16* __restrict__ wt) {
  int idx = blockIdx.x * 256 + threadIdx.x;
  int z = idx >> 17, r = idx & 131071, n = r >> 10, k = r & 1023;
  const float* W = (z == 0) ? Wq : (z == 1) ? Wk : Wv;
  wt[idx] = f2b(W[k * 128 + n]);
}

// C = xb @ Wz^T(stored as Wt[n][k]); 128x128 tile, 4 waves 2x2, 16x16x32 bf16
__global__ __launch_bounds__(256) void k_proj(const u16* __restrict__ xb, const u16* __restrict__ wt,
                                              u16* __restrict__ qb, u16* __restrict__ kb,
                                              u16* __restrict__ vt) {
  int mt = blockIdx.x, z = blockIdx.y;
  int w = threadIdx.x >> 6, lane = threadIdx.x & 63;
  int wr = w >> 1, wc = w & 1;
  int m0 = mt * 128 + wr * 64;
  int n0 = wc * 64;
  int lr = lane & 15, lg = lane >> 4;
  const u16* Wz = wt + z * 131072;
  f32x4 acc[4][4];
  for (int i = 0; i < 4; ++i) for (int j = 0; j < 4; ++j) acc[i][j] = (f32x4){0.f, 0.f, 0.f, 0.f};
  for (int k0 = 0; k0 < 1024; k0 += 32) {
    bf16x8 a[4], bfr[4];
    for (int i = 0; i < 4; ++i)
      a[i] = *(const bf16x8*)(xb + (long)(m0 + i * 16 + lr) * 1024 + k0 + lg * 8);
    for (int j = 0; j < 4; ++j)
      bfr[j] = *(const bf16x8*)(Wz + (long)(n0 + j * 16 + lr) * 1024 + k0 + lg * 8);
    for (int i = 0; i < 4; ++i)
      for (int j = 0; j < 4; ++j)
        acc[i][j] = __builtin_amdgcn_mfma_f32_16x16x32_bf16(a[i], bfr[j], acc[i][j], 0, 0, 0);
  }
  for (int i = 0; i < 4; ++i)
    for (int j = 0; j < 4; ++j)
      for (int r = 0; r < 4; ++r) {
        int m = m0 + i * 16 + lg * 4 + r;   // C layout: row=(lane>>4)*4+reg, col=lane&15
        int n = n0 + j * 16 + lr;
        u16 v = f2b(acc[i][j][r]);
        if (z == 0) qb[(long)m * 128 + n] = v;
        else if (z == 1) kb[(long)m * 128 + n] = v;
        else { int bb = m >> 12, sR = m & 4095; vt[(long)bb * 524288 + (long)n * 4096 + sR] = v; }
      }
}

// flash attention v3: block = (b, 64-row q-tile), 4 waves (16 rows each),
// sequential 64-key tiles; K/V^T staged to LDS via global_load_lds,
// double-buffered, stage(next) issued before compute(cur) (2-phase pipeline).
// XOR chunk-swizzle (involution) applied on the global SOURCE address and on
// the LDS read address; LDS itself written linearly (gload_lds constraint).
__global__ __launch_bounds__(256) void k_attn(const u16* __restrict__ qb, const u16* __restrict__ kb,
                                              const u16* __restrict__ vt, const int* __restrict__ kmask,
                                              float* __restrict__ out) {
  const float SCALE_LOG2 = 0.08838834764831845f * 1.4426950408889634f;
  const float THR = 8.0f;  // defer-max threshold (log2 domain)
  int qt = gridDim.x - 1 - blockIdx.x;  // heavy q-tiles first
  int b = blockIdx.y;
  int w = threadIdx.x >> 6, lane = threadIdx.x & 63;
  int lr = lane & 15, lg = lane >> 4;
  int sw = lr & 7;
  int qBase = qt * 64;
  int qrow0 = qBase + w * 16;
  const u16* Q = qb + ((long)(b * SQ + qrow0)) * HQ;
  const u16* K = kb + (long)b * SQ * HQ;
  const u16* V = vt + (long)b * HQ * SQ;   // V^T: [128][SQ]
  const int* msk = kmask + b * SQ;

  __shared__ __align__(16) u16 Kl[2][64 * 128];   // 2 x 16 KB
  __shared__ __align__(16) u16 Vl[2][128 * 64];   // 2 x 16 KB
  __shared__ __align__(16) u16 plds[4][16][88];   // per-wave P tile, 176B rows

  bf16x8 aq[4];
#pragma unroll
  for (int c = 0; c < 4; ++c) aq[c] = *(const bf16x8*)(Q + lr * HQ + c * 32 + lg * 8);

  f32x4 o[8];
#pragma unroll
  for (int n = 0; n < 8; ++n) o[n] = (f32x4){0.f, 0.f, 0.f, 0.f};
  float m_run[4], l_run[4];
#pragma unroll
  for (int r = 0; r < 4; ++r) { m_run[r] = -3e38f; l_run[r] = 0.f; }

  int nkt = qt + 1;  // 64-key tiles

  // ---- stage tile kt into buffer bufi (8 global_load_lds per wave)
  auto stage = [&](int bufi, int kb0) {
    const u16* Kg = K + (long)kb0 * HQ;
    const u16* Vg = V + kb0;
#pragma unroll
    for (int i = 0; i < 4; ++i) {
      int ci = w * 4 + i;                  // 1KB chunk-group index (K: 16 groups)
      int o16 = ci * 64 + lane;            // 16B-chunk index 0..1023
      int row = o16 >> 4, ch = o16 & 15;   // K tile: 16 chunks per 256B row
      gload_lds16(Kg + row * HQ + ((ch ^ (row & 7)) << 3), &Kl[bufi][ci * 512]);
    }
#pragma unroll
    for (int i = 0; i < 4; ++i) {
      int ci = w * 4 + i;
      int o16 = ci * 64 + lane;
      int row = o16 >> 3, ch = o16 & 7;    // V tile: 8 chunks per 128B row
      gload_lds16(Vg + (long)row * SQ + ((ch ^ (row & 7)) << 3), &Vl[bufi][ci * 512]);
    }
  };

  stage(0, 0);
  __syncthreads();

  for (int kt = 0; kt < nkt; ++kt) {
    int cur = kt & 1;
    int kb0 = kt * 64;
    if (kt + 1 < nkt) stage(cur ^ 1, kb0 + 64);  // prefetch next tile (in flight across compute)

    // ---- QK^T: 16 MFMAs from swizzled LDS
    f32x4 s[4];
#pragma unroll
    for (int h = 0; h < 4; ++h) {
      f32x4 acc = (f32x4){0.f, 0.f, 0.f, 0.f};
      const u16* Kp = &Kl[cur][(h * 16 + lr) * 128];
#pragma unroll
      for (int c = 0; c < 4; ++c) {
        bf16x8 bk = *(const bf16x8*)(Kp + (((c * 4 + lg) ^ sw) << 3));
        acc = __builtin_amdgcn_mfma_f32_16x16x32_bf16(aq[c], bk, acc, 0, 0, 0);
      }
      s[h] = acc;
    }
    int mv[4];
#pragma unroll
    for (int h = 0; h < 4; ++h) mv[h] = msk[kb0 + h * 16 + lr];

    // ---- mask + scale + row-max (shuffle over 16 key-lanes)
    bool diag = (kt == nkt - 1);
    float sv[4][4], tr[4];
#pragma unroll
    for (int r = 0; r < 4; ++r) {
      int qr = qrow0 + lg * 4 + r;
      float tt = -3e38f;
#pragma unroll
      for (int h = 0; h < 4; ++h) {
        bool ok = (mv[h] != 0) && (!diag || (kb0 + h * 16 + lr) <= qr);
        float sx = ok ? s[h][r] * SCALE_LOG2 : -3e38f;
        sv[h][r] = sx;
        tt = fmaxf(tt, sx);
      }
      tt = fmaxf(tt, __shfl_xor(tt, 1));
      tt = fmaxf(tt, __shfl_xor(tt, 2));
      tt = fmaxf(tt, __shfl_xor(tt, 4));
      tt = fmaxf(tt, __shfl_xor(tt, 8));
      tr[r] = tt;
    }
    // ---- defer-max rescale
    bool grow = (tr[0] > m_run[0] + THR) || (tr[1] > m_run[1] + THR) ||
                (tr[2] > m_run[2] + THR) || (tr[3] > m_run[3] + THR);
    if (__any(grow)) {
      float alpha[4];
#pragma unroll
      for (int r = 0; r < 4; ++r) {
        float mnew = fmaxf(m_run[r], tr[r]);
        alpha[r] = __builtin_exp2f(m_run[r] - mnew);
        m_run[r] = mnew;
        l_run[r] *= alpha[r];
      }
#pragma unroll
      for (int n = 0; n < 8; ++n)
#pragma unroll
        for (int r = 0; r < 4; ++r) o[n][r] *= alpha[r];
    }
    // ---- P = exp2(s - m); row-sum; relayout via per-wave LDS tile
#pragma unroll
    for (int r = 0; r < 4; ++r) {
      float rs = 0.f;
#pragma unroll
      for (int h = 0; h < 4; ++h) {
        float p = (sv[h][r] < -1e37f) ? 0.f : __builtin_exp2f(sv[h][r] - m_run[r]);
        plds[w][lg * 4 + r][h * 16 + lr] = f2b(p);
        rs += p;
      }
      rs += __shfl_xor(rs, 1);
      rs += __shfl_xor(rs, 2);
      rs += __shfl_xor(rs, 4);
      rs += __shfl_xor(rs, 8);
      l_run[r] += rs;
    }
    // ---- PV: 16 MFMAs, V^T from swizzled LDS
    bf16x8 ap0 = *(const bf16x8*)(&plds[w][lr][lg * 8]);
    bf16x8 ap1 = *(const bf16x8*)(&plds[w][lr][32 + lg * 8]);
#pragma unroll
    for (int n = 0; n < 8; ++n) {
      const u16* Vp = &Vl[cur][(n * 16 + lr) * 64];
      bf16x8 bv0 = *(const bf16x8*)(Vp + ((lg ^ sw) << 3));
      bf16x8 bv1 = *(const bf16x8*)(Vp + (((4 + lg) ^ sw) << 3));
      o[n] = __builtin_amdgcn_mfma_f32_16x16x32_bf16(ap0, bv0, o[n], 0, 0, 0);
      o[n] = __builtin_amdgcn_mfma_f32_16x16x32_bf16(ap1, bv1, o[n], 0, 0, 0);
    }
    __syncthreads();  // next-tile stage drained (vmcnt) + all waves done with buffers
  }

  // ---- epilogue: normalize and write f32 output
  float invl[4];
#pragma unroll
  for (int r = 0; r < 4; ++r) invl[r] = 1.0f / l_run[r];
#pragma unroll
  for (int n = 0; n < 8; ++n)
#pragma unroll
    for (int r = 0; r < 4; ++r) {
      int qr = qrow0 + lg * 4 + r;
      out[((long)(b * SQ + qr)) * HQ + n * 16 + lr] = o[n][r] * invl[r];
    }
}

extern "C" void kernel_launch(void* const* d_in, const int* in_sizes, int n_in,
                              void* d_out, int out_size, void* d_ws, size_t ws_size,
                              hipStream_t stream) {
  const float* x  = (const float*)d_in[0];
  const float* Wq = (const float*)d_in[1];
  const float* Wk = (const float*)d_in[2];
  const float* Wv = (const float*)d_in[3];
  const int* kmask = (const int*)d_in[4];
  char* ws = (char*)d_ws;
  u16* xb = (u16*)ws;                         // 32 MB: x as bf16
  u16* wt = (u16*)(ws + 33554432);            // 768 KB: Wt[3][128][1024]
  u16* qb = (u16*)(ws + 34340864);            // 4 MB: Q bf16 [16384][128]
  u16* kb = (u16*)(ws + 38535168);            // 4 MB: K bf16 [16384][128]
  u16* vt = (u16*)(ws + 42729472);            // 4 MB: V^T bf16 [4][128][4096]
  float* out = (float*)d_out;

  k_convx<<<8192, 256, 0, stream>>>(x, xb);
  k_wt<<<1536, 256, 0, stream>>>(Wq, Wk, Wv, wt);
  k_proj<<<dim3(128, 3), 256, 0, stream>>>(xb, wt, qb, kb, vt);
  k_attn<<<dim3(64, 4), 256, 0, stream>>>(qb, kb, vt, kmask, out);
}

// Round 4
// 170.518 us; speedup vs baseline: 1.8913x; 1.5492x over previous
//
#include <hip/hip_runtime.h>

typedef unsigned short u16;
typedef __attribute__((ext_vector_type(8))) short bf16x8;
typedef __attribute__((ext_vector_type(4))) float f32x4;
typedef __attribute__((ext_vector_type(8))) unsigned short ushort8;

#define SQ 4096
#define HQ 128
#define NCHUNKF 160   // split-K chunks per batch: sum over qt of (qt/16+1)

__device__ __forceinline__ u16 f2b(float f) {
  unsigned int u = __float_as_uint(f);
  unsigned int r = (u + 0x7fffu + ((u >> 16) & 1u)) >> 16;  // RNE bf16
  return (u16)r;
}

__device__ __forceinline__ void gload_lds16(const u16* gsrc, u16* ldst) {
  __builtin_amdgcn_global_load_lds((const __attribute__((address_space(1))) void*)gsrc,
                                   (__attribute__((address_space(3))) void*)ldst, 16, 0, 0);
}

// x f32 -> bf16, 8 elems/thread
__global__ __launch_bounds__(256) void k_convx(const float* __restrict__ x, u16* __restrict__ xb) {
  long i = (long)(blockIdx.x * 256 + threadIdx.x) * 8;
  float4 a = *(const float4*)(x + i);
  float4 c = *(const float4*)(x + i + 4);
  ushort8 o;
  o[0]=f2b(a.x); o[1]=f2b(a.y); o[2]=f2b(a.z); o[3]=f2b(a.w);
  o[4]=f2b(c.x); o[5]=f2b(c.y); o[6]=f2b(c.z); o[7]=f2b(c.w);
  *(ushort8*)(xb + i) = o;
}

// Wt[z][n][k] = W_z[k][n]  (bf16, B^T layout for MFMA B-frags)
__global__ __launch_bounds__(256) void k_wt(const float* __restrict__ Wq, const float* __restrict__ Wk,
                                            const float* __restrict__ Wv, u16* __restrict__ wt) {
  int idx = blockIdx.x * 256 + threadIdx.x;
  int z = idx >> 17, r = idx & 131071, n = r >> 10, k = r & 1023;
  const float* W = (z == 0) ? Wq : (z == 1) ? Wk : Wv;
  wt[idx] = f2b(W[k * 128 + n]);
}

// C = xb @ Wz^T(stored as Wt[n][k]); 128x128 tile, 4 waves 2x2, 16x16x32 bf16
__global__ __launch_bounds__(256) void k_proj(const u16* __restrict__ xb, const u16* __restrict__ wt,
                                              u16* __restrict__ qb, u16* __restrict__ kb,
                                              u16* __restrict__ vt) {
  int mt = blockIdx.x, z = blockIdx.y;
  int w = threadIdx.x >> 6, lane = threadIdx.x & 63;
  int wr = w >> 1, wc = w & 1;
  int m0 = mt * 128 + wr * 64;
  int n0 = wc * 64;
  int lr = lane & 15, lg = lane >> 4;
  const u16* Wz = wt + z * 131072;
  f32x4 acc[4][4];
  for (int i = 0; i < 4; ++i) for (int j = 0; j < 4; ++j) acc[i][j] = (f32x4){0.f, 0.f, 0.f, 0.f};
  for (int k0 = 0; k0 < 1024; k0 += 32) {
    bf16x8 a[4], bfr[4];
    for (int i = 0; i < 4; ++i)
      a[i] = *(const bf16x8*)(xb + (long)(m0 + i * 16 + lr) * 1024 + k0 + lg * 8);
    for (int j = 0; j < 4; ++j)
      bfr[j] = *(const bf16x8*)(Wz + (long)(n0 + j * 16 + lr) * 1024 + k0 + lg * 8);
    for (int i = 0; i < 4; ++i)
      for (int j = 0; j < 4; ++j)
        acc[i][j] = __builtin_amdgcn_mfma_f32_16x16x32_bf16(a[i], bfr[j], acc[i][j], 0, 0, 0);
  }
  for (int i = 0; i < 4; ++i)
    for (int j = 0; j < 4; ++j)
      for (int r = 0; r < 4; ++r) {
        int m = m0 + i * 16 + lg * 4 + r;   // C layout: row=(lane>>4)*4+reg, col=lane&15
        int n = n0 + j * 16 + lr;
        u16 v = f2b(acc[i][j][r]);
        if (z == 0) qb[(long)m * 128 + n] = v;
        else if (z == 1) kb[(long)m * 128 + n] = v;
        else { int bb = m >> 12, sR = m & 4095; vt[(long)bb * 524288 + (long)n * 4096 + sR] = v; }
      }
}

// flash attention v4: split-K balanced grid. Block = (b, 64-row q-tile, key-chunk
// of <=16 64-key tiles). Fixed-max softmax (log2 m=24, shift-invariant => exact),
// row-sum l via ones-MFMA (no cross-lane shuffles at all). Partial (o,l) -> ws,
// merged linearly by k_merge. K/V^T double-buffered in LDS via global_load_lds
// with XOR chunk-swizzle on global source + swizzled LDS reads.
__global__ __launch_bounds__(256) void k_attn(const u16* __restrict__ qb, const u16* __restrict__ kb,
                                              const u16* __restrict__ vt, const int* __restrict__ kmask,
                                              float* __restrict__ po, float* __restrict__ pl) {
  const float SCALE_LOG2 = 0.08838834764831845f * 1.4426950408889634f;
  const float MFIX = 24.0f;  // fixed softmax shift (log2 domain)
  int f = (NCHUNKF - 1) - (int)blockIdx.x;  // heavy chunks dispatched first
  int b = blockIdx.y;
  // decode f -> (qt, kc): group g = qt/16 has (g+1) chunks per q-tile
  int g = 0;
  while (g < 3 && f >= 8 * (g + 1) * (g + 2)) ++g;
  int off = f - 8 * g * (g + 1);
  int qt = 16 * g + off / (g + 1);
  int kc = off - (off / (g + 1)) * (g + 1);
  int kt0 = kc * 16;
  int kt1 = min(kt0 + 16, qt + 1);

  int w = threadIdx.x >> 6, lane = threadIdx.x & 63;
  int lr = lane & 15, lg = lane >> 4;
  int sw = lr & 7;
  int qrow0 = qt * 64 + w * 16;
  const u16* Q = qb + ((long)(b * SQ + qrow0)) * HQ;
  const u16* K = kb + (long)b * SQ * HQ;
  const u16* V = vt + (long)b * HQ * SQ;   // V^T: [128][SQ]
  const int* msk = kmask + b * SQ;

  __shared__ __align__(16) u16 Kl[2][64 * 128];   // 2 x 16 KB
  __shared__ __align__(16) u16 Vl[2][128 * 64];   // 2 x 16 KB
  __shared__ __align__(16) u16 plds[4][16][88];   // per-wave P tile, 176B rows

  bf16x8 aq[4];
#pragma unroll
  for (int c = 0; c < 4; ++c) aq[c] = *(const bf16x8*)(Q + lr * HQ + c * 32 + lg * 8);

  bf16x8 ones;
#pragma unroll
  for (int e = 0; e < 8; ++e) ones[e] = (short)0x3F80;  // bf16 1.0

  f32x4 o[8];
#pragma unroll
  for (int n = 0; n < 8; ++n) o[n] = (f32x4){0.f, 0.f, 0.f, 0.f};
  f32x4 l_acc = (f32x4){0.f, 0.f, 0.f, 0.f};

  // ---- stage tile at key offset kb0 into buffer bufi (8 global_load_lds/wave)
  auto stage = [&](int bufi, int kb0) {
    const u16* Kg = K + (long)kb0 * HQ;
    const u16* Vg = V + kb0;
#pragma unroll
    for (int i = 0; i < 4; ++i) {
      int ci = w * 4 + i;                  // 1KB chunk-group index
      int o16 = ci * 64 + lane;
      int row = o16 >> 4, ch = o16 & 15;   // K tile: 16 chunks per 256B row
      gload_lds16(Kg + row * HQ + ((ch ^ (row & 7)) << 3), &Kl[bufi][ci * 512]);
    }
#pragma unroll
    for (int i = 0; i < 4; ++i) {
      int ci = w * 4 + i;
      int o16 = ci * 64 + lane;
      int row = o16 >> 3, ch = o16 & 7;    // V tile: 8 chunks per 128B row
      gload_lds16(Vg + (long)row * SQ + ((ch ^ (row & 7)) << 3), &Vl[bufi][ci * 512]);
    }
  };

  stage(0, kt0 * 64);
  __syncthreads();

  for (int kt = kt0; kt < kt1; ++kt) {
    int cur = (kt - kt0) & 1;
    int kb0 = kt * 64;
    if (kt + 1 < kt1) stage(cur ^ 1, kb0 + 64);  // prefetch next tile

    // ---- QK^T: 16 MFMAs from swizzled LDS
    f32x4 s[4];
#pragma unroll
    for (int h = 0; h < 4; ++h) {
      f32x4 acc = (f32x4){0.f, 0.f, 0.f, 0.f};
      const u16* Kp = &Kl[cur][(h * 16 + lr) * 128];
#pragma unroll
      for (int c = 0; c < 4; ++c) {
        bf16x8 bk = *(const bf16x8*)(Kp + (((c * 4 + lg) ^ sw) << 3));
        acc = __builtin_amdgcn_mfma_f32_16x16x32_bf16(aq[c], bk, acc, 0, 0, 0);
      }
      s[h] = acc;
    }
    int mv[4];
#pragma unroll
    for (int h = 0; h < 4; ++h) mv[h] = msk[kb0 + h * 16 + lr];

    // ---- P = exp2(s*scale - MFIX), fixed shift: no max-reduce, no rescale
    bool diag = (kt == qt);
#pragma unroll
    for (int r = 0; r < 4; ++r) {
      int qr = qrow0 + lg * 4 + r;
#pragma unroll
      for (int h = 0; h < 4; ++h) {
        bool ok = (mv[h] != 0) && (!diag || (kb0 + h * 16 + lr) <= qr);
        float sx = ok ? fmaf(s[h][r], SCALE_LOG2, -MFIX) : -200.0f;
        plds[w][lg * 4 + r][h * 16 + lr] = f2b(__builtin_exp2f(sx));
      }
    }
    // ---- P frags; l row-sum via ones-MFMA; PV: 16 MFMAs
    bf16x8 ap0 = *(const bf16x8*)(&plds[w][lr][lg * 8]);
    bf16x8 ap1 = *(const bf16x8*)(&plds[w][lr][32 + lg * 8]);
    l_acc = __builtin_amdgcn_mfma_f32_16x16x32_bf16(ap0, ones, l_acc, 0, 0, 0);
    l_acc = __builtin_amdgcn_mfma_f32_16x16x32_bf16(ap1, ones, l_acc, 0, 0, 0);
#pragma unroll
    for (int n = 0; n < 8; ++n) {
      const u16* Vp = &Vl[cur][(n * 16 + lr) * 64];
      bf16x8 bv0 = *(const bf16x8*)(Vp + ((lg ^ sw) << 3));
      bf16x8 bv1 = *(const bf16x8*)(Vp + (((4 + lg) ^ sw) << 3));
      o[n] = __builtin_amdgcn_mfma_f32_16x16x32_bf16(ap0, bv0, o[n], 0, 0, 0);
      o[n] = __builtin_amdgcn_mfma_f32_16x16x32_bf16(ap1, bv1, o[n], 0, 0, 0);
    }
    __syncthreads();  // stage drained + all waves done with buffers
  }

  // ---- write partials (linear-mergeable thanks to fixed shift)
  long p = (long)b * NCHUNKF + f;
  float* pob = po + p * 8192;  // [64][128]
#pragma unroll
  for (int n = 0; n < 8; ++n)
#pragma unroll
    for (int r = 0; r < 4; ++r)
      pob[(w * 16 + lg * 4 + r) * 128 + n * 16 + lr] = o[n][r];
  if (lr == 0) {
#pragma unroll
    for (int r = 0; r < 4; ++r) pl[p * 64 + w * 16 + lg * 4 + r] = l_acc[r];
  }
}

// merge: out[b, qt*64+row, :] = sum_i po[i] / sum_i pl[i]
__global__ __launch_bounds__(256) void k_merge(const float* __restrict__ po, const float* __restrict__ pl,
                                               float* __restrict__ out) {
  int qt = blockIdx.x, b = blockIdx.y;
  int g = qt >> 4;
  int nch = g + 1;
  long pbase = (long)b * NCHUNKF + 8 * g * (g + 1) + (qt & 15) * (g + 1);
  int t = threadIdx.x;
  int row = t >> 2, c0 = (t & 3) * 32;
  float l = 0.f;
  for (int i = 0; i < nch; ++i) l += pl[(pbase + i) * 64 + row];
  float inv = 1.0f / l;
  const float* po0 = po + pbase * 8192 + row * 128 + c0;
  float* orow = out + ((long)(b * SQ + qt * 64 + row)) * HQ + c0;
#pragma unroll
  for (int j = 0; j < 32; j += 4) {
    float4 acc = {0.f, 0.f, 0.f, 0.f};
    for (int i = 0; i < nch; ++i) {
      float4 v = *(const float4*)(po0 + (long)i * 8192 + j);
      acc.x += v.x; acc.y += v.y; acc.z += v.z; acc.w += v.w;
    }
    acc.x *= inv; acc.y *= inv; acc.z *= inv; acc.w *= inv;
    *(float4*)(orow + j) = acc;
  }
}

extern "C" void kernel_launch(void* const* d_in, const int* in_sizes, int n_in,
                              void* d_out, int out_size, void* d_ws, size_t ws_size,
                              hipStream_t stream) {
  const float* x  = (const float*)d_in[0];
  const float* Wq = (const float*)d_in[1];
  const float* Wk = (const float*)d_in[2];
  const float* Wv = (const float*)d_in[3];
  const int* kmask = (const int*)d_in[4];
  char* ws = (char*)d_ws;
  u16* xb = (u16*)ws;                         // 32 MB: x as bf16 (dead after k_proj)
  u16* wt = (u16*)(ws + 33554432);            // 768 KB: Wt (dead after k_proj)
  u16* qb = (u16*)(ws + 34340864);            // 4 MB: Q bf16
  u16* kb = (u16*)(ws + 38535168);            // 4 MB: K bf16
  u16* vt = (u16*)(ws + 42729472);            // 4 MB: V^T bf16 [4][128][4096]
  float* po = (float*)ws;                     // 21 MB partial O (reuses xb region)
  float* pl = (float*)(ws + 33554432);        // 160 KB partial l (reuses wt region)
  float* out = (float*)d_out;

  k_convx<<<8192, 256, 0, stream>>>(x, xb);
  k_wt<<<1536, 256, 0, stream>>>(Wq, Wk, Wv, wt);
  k_proj<<<dim3(128, 3), 256, 0, stream>>>(xb, wt, qb, kb, vt);
  k_attn<<<dim3(NCHUNKF, 4), 256, 0, stream>>>(qb, kb, vt, kmask, po, pl);
  k_merge<<<dim3(64, 4), 256, 0, stream>>>(po, pl, out);
}

// Round 6
// 130.672 us; speedup vs baseline: 2.4680x; 1.3049x over previous
//
#include <hip/hip_runtime.h>

typedef unsigned short u16;
typedef __attribute__((ext_vector_type(8))) short bf16x8;
typedef __attribute__((ext_vector_type(4))) float f32x4;
typedef __attribute__((ext_vector_type(8))) unsigned short u16x8;
typedef __attribute__((ext_vector_type(4))) unsigned short u16x4;

#define SQ 4096
#define HQ 128
#define NCHUNKF 160   // split-K chunks per batch: sum over qt of (qt/16+1)

__device__ __forceinline__ u16 f2b(float f) {
  unsigned int u = __float_as_uint(f);
  unsigned int r = (u + 0x7fffu + ((u >> 16) & 1u)) >> 16;  // RNE bf16
  return (u16)r;
}

__device__ __forceinline__ void gload_lds16(const u16* gsrc, u16* ldst) {
  __builtin_amdgcn_global_load_lds((const __attribute__((address_space(1))) void*)gsrc,
                                   (__attribute__((address_space(3))) void*)ldst, 16, 0, 0);
}

// Wt[z][n][k] = W_z[k][n]  (bf16, B^T layout for MFMA B-frags)
__global__ __launch_bounds__(256) void k_wt(const float* __restrict__ Wq, const float* __restrict__ Wk,
                                            const float* __restrict__ Wv, u16* __restrict__ wt) {
  int idx = blockIdx.x * 256 + threadIdx.x;
  int z = idx >> 17, r = idx & 131071, n = r >> 10, k = r & 1023;
  const float* W = (z == 0) ? Wq : (z == 1) ? Wk : Wv;
  wt[idx] = f2b(W[k * 128 + n]);
}

// Fused conv+proj: block = 64 x-rows, 512 threads (8 waves 2m x 4n), computes
// Q,K,V (64 x 384) together. x f32 read once, converted in-kernel, staged in
// LDS (reg-staged, swizzled write); W staged via global_load_lds (pre-swizzled
// source). Double-buffered BK=32 pipeline.
__global__ __launch_bounds__(512, 4) void k_proj(const float* __restrict__ x, const u16* __restrict__ wt,
                                                 u16* __restrict__ qb, u16* __restrict__ kb,
                                                 u16* __restrict__ vt) {
  int blk = blockIdx.x;
  int t = threadIdx.x;
  int w = t >> 6, lane = t & 63;
  int wm = w >> 2, wn = w & 3;
  int lr = lane & 15, lg = lane >> 4;

  __shared__ __align__(16) u16 xl[2][64 * 32];    // 2 x 4 KB
  __shared__ __align__(16) u16 wl[2][384 * 32];   // 2 x 24 KB

  // stage assignments
  int srow = t >> 3, sc8 = t & 7;                  // x: row 0..63, 4-f32 group 0..7
  const float* xg = x + (long)(blk * 64 + srow) * 1024 + sc8 * 4;
  int xch = ((sc8 >> 1) ^ ((srow >> 1) & 3));      // swizzled 16B chunk
  int xoff = srow * 32 + xch * 8 + (sc8 & 1) * 4;  // u16 offset within a buffer

  f32x4 acc[2][6];
#pragma unroll
  for (int i = 0; i < 2; ++i)
#pragma unroll
    for (int j = 0; j < 6; ++j) acc[i][j] = (f32x4){0.f, 0.f, 0.f, 0.f};

  // W stage: 3 chunks per thread
  auto stage_w = [&](int bufi, int k0) {
#pragma unroll
    for (int i = 0; i < 3; ++i) {
      int ci = i * 512 + t;                        // 16B chunk id 0..1535
      int row = ci >> 2, ch = ci & 3;              // row n 0..383
      gload_lds16(wt + (long)row * 1024 + k0 + ((ch ^ ((row >> 1) & 3)) << 3),
                  &wl[bufi][0] + ci * 8);
    }
  };

  // prologue: stage step 0
  {
    float4 xa = *(const float4*)(xg);
    stage_w(0, 0);
    u16x4 o;
    o[0] = f2b(xa.x); o[1] = f2b(xa.y); o[2] = f2b(xa.z); o[3] = f2b(xa.w);
    *(u16x4*)(&xl[0][0] + xoff) = o;
  }
  __syncthreads();

  int arow0 = wm * 32 + lr;        // A rows for i=0 (i=1 adds 16)
  for (int ks = 0; ks < 32; ++ks) {
    int cur = ks & 1;
    float4 xa;
    bool more = (ks + 1 < 32);
    if (more) {
      xa = *(const float4*)(xg + (ks + 1) * 32);   // issue early (T14)
      stage_w(cur ^ 1, (ks + 1) * 32);
    }
    // compute from cur
    bf16x8 af[2], bf[6];
#pragma unroll
    for (int i = 0; i < 2; ++i) {
      int row = arow0 + i * 16;
      af[i] = *(const bf16x8*)(&xl[cur][0] + row * 32 + ((lg ^ ((row >> 1) & 3)) << 3));
    }
#pragma unroll
    for (int j = 0; j < 6; ++j) {
      int row = wn * 96 + j * 16 + lr;
      bf[j] = *(const bf16x8*)(&wl[cur][0] + row * 32 + ((lg ^ ((row >> 1) & 3)) << 3));
    }
#pragma unroll
    for (int i = 0; i < 2; ++i)
#pragma unroll
      for (int j = 0; j < 6; ++j)
        acc[i][j] = __builtin_amdgcn_mfma_f32_16x16x32_bf16(af[i], bf[j], acc[i][j], 0, 0, 0);
    // write-late: x for next step
    if (more) {
      u16x4 o;
      o[0] = f2b(xa.x); o[1] = f2b(xa.y); o[2] = f2b(xa.z); o[3] = f2b(xa.w);
      *(u16x4*)(&xl[cur ^ 1][0] + xoff) = o;
    }
    __syncthreads();
  }

  // epilogue: C layout row=(lane>>4)*4+reg, col=lane&15
#pragma unroll
  for (int i = 0; i < 2; ++i)
#pragma unroll
    for (int j = 0; j < 6; ++j)
#pragma unroll
      for (int r = 0; r < 4; ++r) {
        int m = blk * 64 + wm * 32 + i * 16 + lg * 4 + r;
        int col = wn * 96 + j * 16 + lr;
        int z = col >> 7, cz = col & 127;
        u16 v = f2b(acc[i][j][r]);
        if (z == 0) qb[(long)m * 128 + cz] = v;
        else if (z == 1) kb[(long)m * 128 + cz] = v;
        else { int bb = m >> 12, sR = m & 4095; vt[(long)bb * 524288 + (long)cz * 4096 + sR] = v; }
      }
}

// flash attention v4: split-K balanced grid, fixed-max softmax, ones-MFMA
// row-sum, LDS-staged K/V with XOR swizzle, 2-phase pipeline.
__global__ __launch_bounds__(256) void k_attn(const u16* __restrict__ qb, const u16* __restrict__ kb,
                                              const u16* __restrict__ vt, const int* __restrict__ kmask,
                                              float* __restrict__ po, float* __restrict__ pl) {
  const float SCALE_LOG2 = 0.08838834764831845f * 1.4426950408889634f;
  const float MFIX = 24.0f;
  int f = (NCHUNKF - 1) - (int)blockIdx.x;
  int b = blockIdx.y;
  int g = 0;
  while (g < 3 && f >= 8 * (g + 1) * (g + 2)) ++g;
  int off = f - 8 * g * (g + 1);
  int qt = 16 * g + off / (g + 1);
  int kc = off - (off / (g + 1)) * (g + 1);
  int kt0 = kc * 16;
  int kt1 = min(kt0 + 16, qt + 1);

  int w = threadIdx.x >> 6, lane = threadIdx.x & 63;
  int lr = lane & 15, lg = lane >> 4;
  int sw = lr & 7;
  int qrow0 = qt * 64 + w * 16;
  const u16* Q = qb + ((long)(b * SQ + qrow0)) * HQ;
  const u16* K = kb + (long)b * SQ * HQ;
  const u16* V = vt + (long)b * HQ * SQ;
  const int* msk = kmask + b * SQ;

  __shared__ __align__(16) u16 Kl[2][64 * 128];
  __shared__ __align__(16) u16 Vl[2][128 * 64];
  __shared__ __align__(16) u16 plds[4][16][88];

  bf16x8 aq[4];
#pragma unroll
  for (int c = 0; c < 4; ++c) aq[c] = *(const bf16x8*)(Q + lr * HQ + c * 32 + lg * 8);

  bf16x8 ones;
#pragma unroll
  for (int e = 0; e < 8; ++e) ones[e] = (short)0x3F80;

  f32x4 o[8];
#pragma unroll
  for (int n = 0; n < 8; ++n) o[n] = (f32x4){0.f, 0.f, 0.f, 0.f};
  f32x4 l_acc = (f32x4){0.f, 0.f, 0.f, 0.f};

  auto stage = [&](int bufi, int kb0) {
    const u16* Kg = K + (long)kb0 * HQ;
    const u16* Vg = V + kb0;
#pragma unroll
    for (int i = 0; i < 4; ++i) {
      int ci = w * 4 + i;
      int o16 = ci * 64 + lane;
      int row = o16 >> 4, ch = o16 & 15;
      gload_lds16(Kg + row * HQ + ((ch ^ (row & 7)) << 3), &Kl[bufi][ci * 512]);
    }
#pragma unroll
    for (int i = 0; i < 4; ++i) {
      int ci = w * 4 + i;
      int o16 = ci * 64 + lane;
      int row = o16 >> 3, ch = o16 & 7;
      gload_lds16(Vg + (long)row * SQ + ((ch ^ (row & 7)) << 3), &Vl[bufi][ci * 512]);
    }
  };

  stage(0, kt0 * 64);
  __syncthreads();

  for (int kt = kt0; kt < kt1; ++kt) {
    int cur = (kt - kt0) & 1;
    int kb0 = kt * 64;
    if (kt + 1 < kt1) stage(cur ^ 1, kb0 + 64);

    f32x4 s[4];
#pragma unroll
    for (int h = 0; h < 4; ++h) {
      f32x4 acc = (f32x4){0.f, 0.f, 0.f, 0.f};
      const u16* Kp = &Kl[cur][(h * 16 + lr) * 128];
#pragma unroll
      for (int c = 0; c < 4; ++c) {
        bf16x8 bk = *(const bf16x8*)(Kp + (((c * 4 + lg) ^ sw) << 3));
        acc = __builtin_amdgcn_mfma_f32_16x16x32_bf16(aq[c], bk, acc, 0, 0, 0);
      }
      s[h] = acc;
    }
    int mv[4];
#pragma unroll
    for (int h = 0; h < 4; ++h) mv[h] = msk[kb0 + h * 16 + lr];

    bool diag = (kt == qt);
#pragma unroll
    for (int r = 0; r < 4; ++r) {
      int qr = qrow0 + lg * 4 + r;
#pragma unroll
      for (int h = 0; h < 4; ++h) {
        bool ok = (mv[h] != 0) && (!diag || (kb0 + h * 16 + lr) <= qr);
        float sx = ok ? fmaf(s[h][r], SCALE_LOG2, -MFIX) : -200.0f;
        plds[w][lg * 4 + r][h * 16 + lr] = f2b(__builtin_exp2f(sx));
      }
    }
    bf16x8 ap0 = *(const bf16x8*)(&plds[w][lr][lg * 8]);
    bf16x8 ap1 = *(const bf16x8*)(&plds[w][lr][32 + lg * 8]);
    l_acc = __builtin_amdgcn_mfma_f32_16x16x32_bf16(ap0, ones, l_acc, 0, 0, 0);
    l_acc = __builtin_amdgcn_mfma_f32_16x16x32_bf16(ap1, ones, l_acc, 0, 0, 0);
#pragma unroll
    for (int n = 0; n < 8; ++n) {
      const u16* Vp = &Vl[cur][(n * 16 + lr) * 64];
      bf16x8 bv0 = *(const bf16x8*)(Vp + ((lg ^ sw) << 3));
      bf16x8 bv1 = *(const bf16x8*)(Vp + (((4 + lg) ^ sw) << 3));
      o[n] = __builtin_amdgcn_mfma_f32_16x16x32_bf16(ap0, bv0, o[n], 0, 0, 0);
      o[n] = __builtin_amdgcn_mfma_f32_16x16x32_bf16(ap1, bv1, o[n], 0, 0, 0);
    }
    __syncthreads();
  }

  long p = (long)b * NCHUNKF + f;
  float* pob = po + p * 8192;
#pragma unroll
  for (int n = 0; n < 8; ++n)
#pragma unroll
    for (int r = 0; r < 4; ++r)
      pob[(w * 16 + lg * 4 + r) * 128 + n * 16 + lr] = o[n][r];
  if (lr == 0) {
#pragma unroll
    for (int r = 0; r < 4; ++r) pl[p * 64 + w * 16 + lg * 4 + r] = l_acc[r];
  }
}

// merge: out[b, qt*64+row, :] = sum_i po[i] / sum_i pl[i]
__global__ __launch_bounds__(256) void k_merge(const float* __restrict__ po, const float* __restrict__ pl,
                                               float* __restrict__ out) {
  int qt = blockIdx.x, b = blockIdx.y;
  int g = qt >> 4;
  int nch = g + 1;
  long pbase = (long)b * NCHUNKF + 8 * g * (g + 1) + (qt & 15) * (g + 1);
  int t = threadIdx.x;
  int row = t >> 2, c0 = (t & 3) * 32;
  float l = 0.f;
  for (int i = 0; i < nch; ++i) l += pl[(pbase + i) * 64 + row];
  float inv = 1.0f / l;
  const float* po0 = po + pbase * 8192 + row * 128 + c0;
  float* orow = out + ((long)(b * SQ + qt * 64 + row)) * HQ + c0;
#pragma unroll
  for (int j = 0; j < 32; j += 4) {
    float4 acc = {0.f, 0.f, 0.f, 0.f};
    for (int i = 0; i < nch; ++i) {
      float4 v = *(const float4*)(po0 + (long)i * 8192 + j);
      acc.x += v.x; acc.y += v.y; acc.z += v.z; acc.w += v.w;
    }
    acc.x *= inv; acc.y *= inv; acc.z *= inv; acc.w *= inv;
    *(float4*)(orow + j) = acc;
  }
}

extern "C" void kernel_launch(void* const* d_in, const int* in_sizes, int n_in,
                              void* d_out, int out_size, void* d_ws, size_t ws_size,
                              hipStream_t stream) {
  const float* x  = (const float*)d_in[0];
  const float* Wq = (const float*)d_in[1];
  const float* Wk = (const float*)d_in[2];
  const float* Wv = (const float*)d_in[3];
  const int* kmask = (const int*)d_in[4];
  char* ws = (char*)d_ws;
  u16* wt = (u16*)(ws + 33554432);            // 768 KB: Wt (dead after k_proj)
  u16* qb = (u16*)(ws + 34340864);            // 4 MB: Q bf16
  u16* kb = (u16*)(ws + 38535168);            // 4 MB: K bf16
  u16* vt = (u16*)(ws + 42729472);            // 4 MB: V^T bf16 [4][128][4096]
  float* po = (float*)ws;                     // 21 MB partial O
  float* pl = (float*)(ws + 33554432);        // 160 KB partial l (reuses wt region)
  float* out = (float*)d_out;

  k_wt<<<1536, 256, 0, stream>>>(Wq, Wk, Wv, wt);
  k_proj<<<256, 512, 0, stream>>>(x, wt, qb, kb, vt);
  k_attn<<<dim3(NCHUNKF, 4), 256, 0, stream>>>(qb, kb, vt, kmask, po, pl);
  k_merge<<<dim3(64, 4), 256, 0, stream>>>(po, pl, out);
}

// Round 8
// 127.284 us; speedup vs baseline: 2.5337x; 1.0266x over previous
//
#include <hip/hip_runtime.h>
#include <hip/hip_bf16.h>

typedef unsigned short u16;
typedef __attribute__((ext_vector_type(8))) short bf16x8;
typedef __attribute__((ext_vector_type(4))) float f32x4;
typedef __attribute__((ext_vector_type(4))) unsigned short u16x4;

#define SQ 4096
#define HQ 128
#define NCHUNK 80   // split-K chunks per batch (QBLK=128, chunk<=16 key-tiles)

__device__ __forceinline__ u16 f2b(float f) {
  unsigned int u = __float_as_uint(f);
  unsigned int r = (u + 0x7fffu + ((u >> 16) & 1u)) >> 16;  // RNE bf16
  return (u16)r;
}

__device__ __forceinline__ u16 f2b_fast(float f) {
  __hip_bfloat16 h = __float2bfloat16(f);   // compiler pairs into v_cvt_pk_bf16_f32
  return __builtin_bit_cast(u16, h);
}

__device__ __forceinline__ void gload_lds16(const u16* gsrc, u16* ldst) {
  __builtin_amdgcn_global_load_lds((const __attribute__((address_space(1))) void*)gsrc,
                                   (__attribute__((address_space(3))) void*)ldst, 16, 0, 0);
}

// Wt[z][n][k] = W_z[k][n]  (bf16, B^T layout for MFMA B-frags)
__global__ __launch_bounds__(256) void k_wt(const float* __restrict__ Wq, const float* __restrict__ Wk,
                                            const float* __restrict__ Wv, u16* __restrict__ wt) {
  int idx = blockIdx.x * 256 + threadIdx.x;
  int z = idx >> 17, r = idx & 131071, n = r >> 10, k = r & 1023;
  const float* W = (z == 0) ? Wq : (z == 1) ? Wk : Wv;
  wt[idx] = f2b(W[k * 128 + n]);
}

// Fused conv+proj: 64 x-rows/block, 8 waves, Q/K/V together.
__global__ __launch_bounds__(512, 4) void k_proj(const float* __restrict__ x, const u16* __restrict__ wt,
                                                 u16* __restrict__ qb, u16* __restrict__ kb,
                                                 u16* __restrict__ vt) {
  int blk = blockIdx.x;
  int t = threadIdx.x;
  int w = t >> 6, lane = t & 63;
  int wm = w >> 2, wn = w & 3;
  int lr = lane & 15, lg = lane >> 4;

  __shared__ __align__(16) u16 xl[2][64 * 32];    // 2 x 4 KB
  __shared__ __align__(16) u16 wl[2][384 * 32];   // 2 x 24 KB

  int srow = t >> 3, sc8 = t & 7;
  const float* xg = x + (long)(blk * 64 + srow) * 1024 + sc8 * 4;
  int xch = ((sc8 >> 1) ^ ((srow >> 1) & 3));
  int xoff = srow * 32 + xch * 8 + (sc8 & 1) * 4;

  f32x4 acc[2][6];
#pragma unroll
  for (int i = 0; i < 2; ++i)
#pragma unroll
    for (int j = 0; j < 6; ++j) acc[i][j] = (f32x4){0.f, 0.f, 0.f, 0.f};

  auto stage_w = [&](int bufi, int k0) {
#pragma unroll
    for (int i = 0; i < 3; ++i) {
      int ci = i * 512 + t;
      int row = ci >> 2, ch = ci & 3;
      gload_lds16(wt + (long)row * 1024 + k0 + ((ch ^ ((row >> 1) & 3)) << 3),
                  &wl[bufi][0] + ci * 8);
    }
  };

  {
    float4 xa = *(const float4*)(xg);
    stage_w(0, 0);
    u16x4 o;
    o[0] = f2b(xa.x); o[1] = f2b(xa.y); o[2] = f2b(xa.z); o[3] = f2b(xa.w);
    *(u16x4*)(&xl[0][0] + xoff) = o;
  }
  __syncthreads();

  int arow0 = wm * 32 + lr;
  for (int ks = 0; ks < 32; ++ks) {
    int cur = ks & 1;
    float4 xa;
    bool more = (ks + 1 < 32);
    if (more) {
      xa = *(const float4*)(xg + (ks + 1) * 32);
      stage_w(cur ^ 1, (ks + 1) * 32);
    }
    bf16x8 af[2], bf[6];
#pragma unroll
    for (int i = 0; i < 2; ++i) {
      int row = arow0 + i * 16;
      af[i] = *(const bf16x8*)(&xl[cur][0] + row * 32 + ((lg ^ ((row >> 1) & 3)) << 3));
    }
#pragma unroll
    for (int j = 0; j < 6; ++j) {
      int row = wn * 96 + j * 16 + lr;
      bf[j] = *(const bf16x8*)(&wl[cur][0] + row * 32 + ((lg ^ ((row >> 1) & 3)) << 3));
    }
#pragma unroll
    for (int i = 0; i < 2; ++i)
#pragma unroll
      for (int j = 0; j < 6; ++j)
        acc[i][j] = __builtin_amdgcn_mfma_f32_16x16x32_bf16(af[i], bf[j], acc[i][j], 0, 0, 0);
    if (more) {
      u16x4 o;
      o[0] = f2b(xa.x); o[1] = f2b(xa.y); o[2] = f2b(xa.z); o[3] = f2b(xa.w);
      *(u16x4*)(&xl[cur ^ 1][0] + xoff) = o;
    }
    __syncthreads();
  }

#pragma unroll
  for (int i = 0; i < 2; ++i)
#pragma unroll
    for (int j = 0; j < 6; ++j)
#pragma unroll
      for (int r = 0; r < 4; ++r) {
        int m = blk * 64 + wm * 32 + i * 16 + lg * 4 + r;
        int col = wn * 96 + j * 16 + lr;
        int z = col >> 7, cz = col & 127;
        u16 v = f2b(acc[i][j][r]);
        if (z == 0) qb[(long)m * 128 + cz] = v;
        else if (z == 1) kb[(long)m * 128 + cz] = v;
        else { int bb = m >> 12, sR = m & 4095; vt[(long)bb * 524288 + (long)cz * 4096 + sR] = v; }
      }
}

// flash attention v5.1: 8-wave blocks (512 thr) share K/V staging. QBLK=128
// rows (16/wave), KVBLK=64, split-K chunks of <=16 tiles. Fixed-max softmax,
// ones-MFMA row-sum, wave-uniform causal specialization (full/masked/skip),
// double-buffered K&V via global_load_lds (pre-swizzled source), 1 barrier/iter.
__global__ __launch_bounds__(512, 4) void k_attn(const u16* __restrict__ qb, const u16* __restrict__ kb,
                                                 const u16* __restrict__ vt, const int* __restrict__ kmask,
                                                 float* __restrict__ po, float* __restrict__ pl) {
  const float SCALE_LOG2 = 0.08838834764831845f * 1.4426950408889634f;
  const float MFIX = 24.0f;
  int f = (NCHUNK - 1) - (int)blockIdx.x;  // heavy chunks first
  int b = blockIdx.y;
  // decode f -> (qt2, kc): group gg = qt2>>3 has gg+1 chunks per q-tile
  int gg = 0;
  while (gg < 3 && f >= 4 * (gg + 1) * (gg + 2)) ++gg;
  int off = f - 4 * gg * (gg + 1);
  int qt2 = 8 * gg + off / (gg + 1);
  int kc = off - (off / (gg + 1)) * (gg + 1);
  int kt0 = kc * 16;
  int kt1 = min(kt0 + 16, 2 * qt2 + 2);

  int t = threadIdx.x, w = t >> 6, lane = t & 63;
  int lr = lane & 15, lg = lane >> 4, sw = lr & 7;
  int qrow0 = qt2 * 128 + w * 16;
  const u16* Q = qb + ((long)(b * SQ + qrow0)) * HQ;
  const u16* K = kb + (long)b * SQ * HQ;
  const u16* V = vt + (long)b * HQ * SQ;   // V^T: [128][SQ]
  const int* msk = kmask + b * SQ;

  __shared__ __align__(16) u16 Kl[2][64 * 128];   // 2 x 16 KB
  __shared__ __align__(16) u16 Vl[2][128 * 64];   // 2 x 16 KB
  __shared__ __align__(16) u16 plds[8][16 * 64];  // 16 KB, XOR-chunk layout

  bf16x8 aq[4];
#pragma unroll
  for (int c = 0; c < 4; ++c) aq[c] = *(const bf16x8*)(Q + lr * HQ + c * 32 + lg * 8);

  bf16x8 ones;
#pragma unroll
  for (int e = 0; e < 8; ++e) ones[e] = (short)0x3F80;

  f32x4 o[8];
#pragma unroll
  for (int n = 0; n < 8; ++n) o[n] = (f32x4){0.f, 0.f, 0.f, 0.f};
  f32x4 l_acc = (f32x4){0.f, 0.f, 0.f, 0.f};

  // stage one 64-key tile (K: 1024 chunks, V: 1024 chunks; 2+2 per thread)
  auto stage = [&](int bufi, int kb0) {
    const u16* Kg = K + (long)kb0 * HQ;
    const u16* Vg = V + kb0;
#pragma unroll
    for (int i = 0; i < 2; ++i) {
      int ci = w * 2 + i;
      int o16 = ci * 64 + lane;
      int row = o16 >> 4, ch = o16 & 15;     // K: 16 chunks per 256B row
      gload_lds16(Kg + row * HQ + ((ch ^ (row & 7)) << 3), &Kl[bufi][ci * 512]);
    }
#pragma unroll
    for (int i = 0; i < 2; ++i) {
      int ci = 16 + w * 2 + i;
      int o16 = (ci - 16) * 64 + lane;
      int row = o16 >> 3, ch = o16 & 7;      // V: 8 chunks per 128B row
      gload_lds16(Vg + (long)row * SQ + ((ch ^ (row & 7)) << 3), &Vl[bufi][(ci - 16) * 512]);
    }
  };

  stage(0, kt0 * 64);
  __syncthreads();

  u16* pw = &plds[w][0];
  for (int kt = kt0; kt < kt1; ++kt) {
    int cur = (kt - kt0) & 1;
    int kb0 = kt * 64;
    if (kt + 1 < kt1) stage(cur ^ 1, kb0 + 64);

    if (kb0 <= qrow0 + 15) {                 // wave-uniform: any valid keys in tile?
      // ---- QK^T: 16 MFMAs from swizzled LDS
      f32x4 s[4];
#pragma unroll
      for (int h = 0; h < 4; ++h) {
        f32x4 acc = (f32x4){0.f, 0.f, 0.f, 0.f};
        const u16* Kp = &Kl[cur][(h * 16 + lr) * 128];
#pragma unroll
        for (int c = 0; c < 4; ++c) {
          bf16x8 bk = *(const bf16x8*)(Kp + (((c * 4 + lg) ^ sw) << 3));
          acc = __builtin_amdgcn_mfma_f32_16x16x32_bf16(aq[c], bk, acc, 0, 0, 0);
        }
        s[h] = acc;
      }
      float mf[4];
#pragma unroll
      for (int h = 0; h < 4; ++h) mf[h] = (msk[kb0 + h * 16 + lr] != 0) ? 1.0f : 0.0f;
      bool needc = (kb0 + 63 > qrow0);       // full tile only if max key <= min q row
      // ---- P = exp2(s*scale - MFIX) * mask; write to XOR-chunk plds
#pragma unroll
      for (int r = 0; r < 4; ++r) {
        int row = lg * 4 + r;
        int qr = qrow0 + row;
#pragma unroll
        for (int h = 0; h < 4; ++h) {
          float p = __builtin_exp2f(fmaf(s[h][r], SCALE_LOG2, -MFIX)) * mf[h];
          if (needc) p = ((kb0 + h * 16 + lr) <= qr) ? p : 0.0f;
          int poff = row * 64 + ((((h * 2 + (lr >> 3)) ^ (row & 7))) << 3) + (lr & 7);
          pw[poff] = f2b_fast(p);
        }
      }
      // ---- P frags; l via ones-MFMA; PV: 16 MFMAs
      bf16x8 ap0 = *(const bf16x8*)(pw + lr * 64 + ((lg ^ sw) << 3));
      bf16x8 ap1 = *(const bf16x8*)(pw + lr * 64 + (((4 + lg) ^ sw) << 3));
      l_acc = __builtin_amdgcn_mfma_f32_16x16x32_bf16(ap0, ones, l_acc, 0, 0, 0);
      l_acc = __builtin_amdgcn_mfma_f32_16x16x32_bf16(ap1, ones, l_acc, 0, 0, 0);
#pragma unroll
      for (int n = 0; n < 8; ++n) {
        const u16* Vp = &Vl[cur][(n * 16 + lr) * 64];
        bf16x8 bv0 = *(const bf16x8*)(Vp + ((lg ^ sw) << 3));
        bf16x8 bv1 = *(const bf16x8*)(Vp + (((4 + lg) ^ sw) << 3));
        o[n] = __builtin_amdgcn_mfma_f32_16x16x32_bf16(ap0, bv0, o[n], 0, 0, 0);
        o[n] = __builtin_amdgcn_mfma_f32_16x16x32_bf16(ap1, bv1, o[n], 0, 0, 0);
      }
    }
    __syncthreads();  // stage drained + all waves done with buffers
  }

  // ---- write partials
  long p = (long)b * NCHUNK + f;
  float* pob = po + p * 16384;  // [128][128]
#pragma unroll
  for (int n = 0; n < 8; ++n)
#pragma unroll
    for (int r = 0; r < 4; ++r)
      pob[(w * 16 + lg * 4 + r) * 128 + n * 16 + lr] = o[n][r];
  if (lr == 0) {
#pragma unroll
    for (int r = 0; r < 4; ++r) pl[p * 128 + w * 16 + lg * 4 + r] = l_acc[r];
  }
}

// merge: out[b, qt2*128+row, :] = sum_i po[i] / sum_i pl[i]
__global__ __launch_bounds__(256) void k_merge(const float* __restrict__ po, const float* __restrict__ pl,
                                               float* __restrict__ out) {
  int qt2 = blockIdx.x, b = blockIdx.y;
  int gg = qt2 >> 3;
  int nch = gg + 1;
  long pbase = (long)b * NCHUNK + 4 * gg * (gg + 1) + (qt2 & 7) * (gg + 1);
  int t = threadIdx.x;
  int row = t >> 1, c0 = (t & 1) * 64;
  float l = 0.f;
  for (int i = 0; i < nch; ++i) l += pl[(pbase + i) * 128 + row];
  float inv = 1.0f / l;
  const float* p0 = po + pbase * 16384 + row * 128 + c0;
  float* orow = out + ((long)(b * SQ + qt2 * 128 + row)) * HQ + c0;
#pragma unroll
  for (int j = 0; j < 64; j += 4) {
    float4 acc = {0.f, 0.f, 0.f, 0.f};
    for (int i = 0; i < nch; ++i) {
      float4 v = *(const float4*)(p0 + (long)i * 16384 + j);
      acc.x += v.x; acc.y += v.y; acc.z += v.z; acc.w += v.w;
    }
    acc.x *= inv; acc.y *= inv; acc.z *= inv; acc.w *= inv;
    *(float4*)(orow + j) = acc;
  }
}

extern "C" void kernel_launch(void* const* d_in, const int* in_sizes, int n_in,
                              void* d_out, int out_size, void* d_ws, size_t ws_size,
                              hipStream_t stream) {
  const float* x  = (const float*)d_in[0];
  const float* Wq = (const float*)d_in[1];
  const float* Wk = (const float*)d_in[2];
  const float* Wv = (const float*)d_in[3];
  const int* kmask = (const int*)d_in[4];
  char* ws = (char*)d_ws;
  u16* wt = (u16*)(ws + 33554432);            // 768 KB: Wt (dead after k_proj)
  u16* qb = (u16*)(ws + 34340864);            // 4 MB: Q bf16
  u16* kb = (u16*)(ws + 38535168);            // 4 MB: K bf16
  u16* vt = (u16*)(ws + 42729472);            // 4 MB: V^T bf16 [4][128][4096]
  float* po = (float*)ws;                     // 21 MB partial O (reuses 0..32MB)
  float* pl = (float*)(ws + 33554432);        // 160 KB partial l (reuses wt region)
  float* out = (float*)d_out;

  k_wt<<<1536, 256, 0, stream>>>(Wq, Wk, Wv, wt);
  k_proj<<<256, 512, 0, stream>>>(x, wt, qb, kb, vt);
  k_attn<<<dim3(NCHUNK, 4), 512, 0, stream>>>(qb, kb, vt, kmask, po, pl);
  k_merge<<<dim3(32, 4), 256, 0, stream>>>(po, pl, out);
}